// Round 1
// baseline (453.576 us; speedup 1.0000x reference)
//
#include <hip/hip_runtime.h>
#include <hip/hip_bf16.h>

#define NB     32
#define TLEN   4096
#define ENCH   512
#define ATTH   256
#define DECH   512
#define OUTD   80
#define SPKD   64
#define KW     31
#define ATTR   10

// ---------------------------------------------------------------------------
// Kernel A: per-batch block. Zero output row, argmax(prev_attention),
// prenet chain -> per-batch bias[256] = out_prenet@W_dec + softsign(spkr@W_spkr)
//                                      + speed*W_speed
// ---------------------------------------------------------------------------
__global__ __launch_bounds__(1024) void prep_kernel(
    const float* __restrict__ pa,        // [N,T]
    const float* __restrict__ input_dec, // [N,80]
    const float* __restrict__ spkr_vec,  // [N,64]
    const float* __restrict__ speed,     // [N]
    const float* __restrict__ Wp1,       // [144,1024]
    const float* __restrict__ bp1,       // [1024]
    const float* __restrict__ Wp2,       // [1024,512]
    const float* __restrict__ bp2,       // [512]
    const float* __restrict__ W_dec,     // [512,256]
    const float* __restrict__ W_spkr,    // [64,256]
    const float* __restrict__ W_speed,   // [256]
    float* __restrict__ out,             // [N,T]
    int* __restrict__ ws_idx,            // [N]
    float* __restrict__ ws_bias)         // [N,256]
{
  const int n   = blockIdx.x;
  const int tid = threadIdx.x;

  __shared__ float s_dec[144];
  __shared__ float s_h1[1024];
  __shared__ float s_op[512];
  __shared__ __align__(16) float s_red[8 * 512];
  __shared__ float s_av[1024];
  __shared__ int   s_ai[1024];

  // ---- zero the output row (harness poisons d_out with 0xAA every launch)
  {
    float4* o4 = (float4*)(out + (size_t)n * TLEN);
    o4[tid] = make_float4(0.f, 0.f, 0.f, 0.f);
  }

  // ---- stage dec_in = concat(input_dec, spkr_vec) into LDS
  if (tid < OUTD)      s_dec[tid] = input_dec[n * OUTD + tid];
  else if (tid < 144)  s_dec[tid] = spkr_vec[n * SPKD + (tid - OUTD)];

  // ---- argmax over prev_attention[n,:] (first occurrence on ties)
  {
    const float* p = pa + (size_t)n * TLEN;
    float bv = -1.f; int bi = 0;
    #pragma unroll
    for (int k = 0; k < TLEN / 1024; k++) {
      int t = tid + k * 1024;        // increasing t: strict > keeps first index
      float v = p[t];
      if (v > bv) { bv = v; bi = t; }
    }
    s_av[tid] = bv; s_ai[tid] = bi;
    __syncthreads();
    for (int s = 512; s > 0; s >>= 1) {
      if (tid < s) {
        float ov = s_av[tid + s]; int oi = s_ai[tid + s];
        float mv = s_av[tid];     int mi = s_ai[tid];
        if (ov > mv || (ov == mv && oi < mi)) { s_av[tid] = ov; s_ai[tid] = oi; }
      }
      __syncthreads();
    }
    if (tid == 0) ws_idx[n] = s_ai[0];
  }

  // ---- h1 = relu(dec_in @ Wp1 + bp1)   (one output per thread)
  {
    float acc = bp1[tid];
    #pragma unroll 4
    for (int i = 0; i < 144; i++)
      acc = fmaf(s_dec[i], Wp1[i * 1024 + tid], acc);
    s_h1[tid] = fmaxf(acc, 0.f);
  }
  __syncthreads();

  // ---- out_prenet = relu(h1 @ Wp2 + bp2)
  // 128 groups of 4 consecutive k (float4 loads), 8-way K-split over j
  {
    const int g = tid & 127, sl = tid >> 7;
    const int k0 = g * 4;
    float4 acc = make_float4(0.f, 0.f, 0.f, 0.f);
    for (int j = sl; j < 1024; j += 8) {
      float hv = s_h1[j];
      float4 w = *(const float4*)(Wp2 + (size_t)j * 512 + k0);
      acc.x = fmaf(hv, w.x, acc.x);
      acc.y = fmaf(hv, w.y, acc.y);
      acc.z = fmaf(hv, w.z, acc.z);
      acc.w = fmaf(hv, w.w, acc.w);
    }
    *(float4*)(s_red + sl * 512 + k0) = acc;
    __syncthreads();
    if (tid < 512) {
      float v = bp2[tid];
      #pragma unroll
      for (int s2 = 0; s2 < 8; s2++) v += s_red[s2 * 512 + tid];
      s_op[tid] = fmaxf(v, 0.f);
    }
    __syncthreads();
  }

  // ---- bias = out_prenet @ W_dec + softsign(spkr @ W_spkr) + speed*W_speed
  {
    const int c = tid & 255, sl = tid >> 8;   // 4-way K-split over k
    float acc = 0.f;
    const int kb = sl * 128;
    #pragma unroll 4
    for (int k = kb; k < kb + 128; k++)
      acc = fmaf(s_op[k], W_dec[k * 256 + c], acc);
    s_red[sl * 256 + c] = acc;
    __syncthreads();
    if (tid < 256) {
      float b = s_red[tid] + s_red[256 + tid] + s_red[512 + tid] + s_red[768 + tid];
      float sp = 0.f;
      #pragma unroll 4
      for (int i = 0; i < 64; i++)
        sp = fmaf(s_dec[OUTD + i], W_spkr[i * 256 + tid], sp);
      sp = sp / (1.f + fabsf(sp));
      b += sp + speed[n] * W_speed[tid];
      ws_bias[n * 256 + tid] = b;
    }
  }
}

// ---------------------------------------------------------------------------
// Kernel B: band logits. Block (n, jb) computes 4 band positions t = lo+4*jb+q.
// logit[t] = sum_c tanh( softsign(enc_row@W_enc + b_enc)[c] + bias[c] + conv[t,c] ) * W_proj[c]
// (b_proj omitted: constant per batch, cancels in softmax)
// ---------------------------------------------------------------------------
__global__ __launch_bounds__(256) void band_kernel(
    const float* __restrict__ input_enc, // [N,T,512]
    const float* __restrict__ pa,        // [N,T]
    const int*   __restrict__ lengths,   // [N]
    const float* __restrict__ W_enc,     // [512,256]
    const float* __restrict__ b_enc,     // [256]
    const float* __restrict__ conv_w,    // [256,31]
    const float* __restrict__ W_proj,    // [256]
    const int*   __restrict__ ws_idx,    // [N]
    const float* __restrict__ ws_bias,   // [N,256]
    float* __restrict__ ws_logits)       // [N,20]
{
  const int n  = blockIdx.x;
  const int jb = blockIdx.y;
  const int tid = threadIdx.x;

  const int mi  = ws_idx[n];
  const int len = lengths[n];
  const int lo  = max(mi - (ATTR - 1), 0);
  const int hi  = min(mi + (ATTR - 1), len - 1);
  const int t0  = lo + jb * 4;

  __shared__ float s_enc[4][ENCH];
  __shared__ float s_pa[34];
  __shared__ float s_part[4][4];

  #pragma unroll
  for (int q = 0; q < 4; q++) {
    int t = t0 + q;
    bool valid = (t <= hi);
    const float* src = input_enc + ((size_t)n * TLEN + t) * ENCH;
    s_enc[q][tid]       = valid ? src[tid]       : 0.f;
    s_enc[q][tid + 256] = valid ? src[tid + 256] : 0.f;
  }
  if (tid < 34) {
    int idx = t0 - (KW / 2) + tid;
    s_pa[tid] = (idx >= 0 && idx < TLEN) ? pa[(size_t)n * TLEN + idx] : 0.f;
  }
  __syncthreads();

  const int c = tid;
  float a0 = 0.f, a1 = 0.f, a2 = 0.f, a3 = 0.f;
  #pragma unroll 8
  for (int i = 0; i < ENCH; i++) {
    float w = W_enc[i * 256 + c];
    a0 = fmaf(s_enc[0][i], w, a0);
    a1 = fmaf(s_enc[1][i], w, a1);
    a2 = fmaf(s_enc[2][i], w, a2);
    a3 = fmaf(s_enc[3][i], w, a3);
  }

  float c0 = 0.f, c1 = 0.f, c2 = 0.f, c3 = 0.f;
  #pragma unroll
  for (int k = 0; k < KW; k++) {
    float w = conv_w[c * KW + k];
    c0 = fmaf(s_pa[0 + k], w, c0);
    c1 = fmaf(s_pa[1 + k], w, c1);
    c2 = fmaf(s_pa[2 + k], w, c2);
    c3 = fmaf(s_pa[3 + k], w, c3);
  }

  const float be   = b_enc[c];
  const float bias = ws_bias[n * 256 + c];
  const float wp   = W_proj[c];

  float v[4];
  {
    float s0 = a0 + be; s0 = s0 / (1.f + fabsf(s0)); v[0] = tanhf(s0 + bias + c0) * wp;
    float s1 = a1 + be; s1 = s1 / (1.f + fabsf(s1)); v[1] = tanhf(s1 + bias + c1) * wp;
    float s2 = a2 + be; s2 = s2 / (1.f + fabsf(s2)); v[2] = tanhf(s2 + bias + c2) * wp;
    float s3 = a3 + be; s3 = s3 / (1.f + fabsf(s3)); v[3] = tanhf(s3 + bias + c3) * wp;
  }

  const int lane = tid & 63, wv = tid >> 6;
  #pragma unroll
  for (int q = 0; q < 4; q++) {
    float x = v[q];
    #pragma unroll
    for (int off = 32; off > 0; off >>= 1) x += __shfl_down(x, off);
    if (lane == 0) s_part[wv][q] = x;
  }
  __syncthreads();
  if (tid < 4) {
    float s = s_part[0][tid] + s_part[1][tid] + s_part[2][tid] + s_part[3][tid];
    int j = jb * 4 + tid;
    int t = t0 + tid;
    ws_logits[n * 20 + j] = (t <= hi) ? s : -__builtin_inff();
  }
}

// ---------------------------------------------------------------------------
// Kernel C: band softmax + scatter (global max shift cancels; band max used)
// ---------------------------------------------------------------------------
__global__ __launch_bounds__(64) void softmax_kernel(
    const float* __restrict__ ws_logits, // [N,20]
    const int*   __restrict__ ws_idx,    // [N]
    const int*   __restrict__ lengths,   // [N]
    float* __restrict__ out)             // [N,T]
{
  const int n = blockIdx.x;
  const int tid = threadIdx.x;
  const int mi  = ws_idx[n];
  const int len = lengths[n];
  const int lo  = max(mi - (ATTR - 1), 0);
  const int hi  = min(mi + (ATTR - 1), len - 1);

  float l = (tid < 20) ? ws_logits[n * 20 + tid] : -__builtin_inff();
  float m = l;
  #pragma unroll
  for (int off = 32; off > 0; off >>= 1) m = fmaxf(m, __shfl_down(m, off));
  m = __shfl(m, 0);
  float e = __expf(l - m);           // -inf -> 0
  float s = e;
  #pragma unroll
  for (int off = 32; off > 0; off >>= 1) s += __shfl_down(s, off);
  s = __shfl(s, 0);

  int t = lo + tid;
  if (tid < 20 && t <= hi)
    out[(size_t)n * TLEN + t] = e / s;
}

// ---------------------------------------------------------------------------
extern "C" void kernel_launch(void* const* d_in, const int* in_sizes, int n_in,
                              void* d_out, int out_size, void* d_ws, size_t ws_size,
                              hipStream_t stream) {
  const float* input_enc = (const float*)d_in[0];
  const float* input_dec = (const float*)d_in[1];
  const float* pa        = (const float*)d_in[2];
  const float* spkr_vec  = (const float*)d_in[3];
  const int*   lengths   = (const int*)  d_in[4];
  const float* speed     = (const float*)d_in[5];
  const float* W_enc     = (const float*)d_in[6];
  const float* b_enc     = (const float*)d_in[7];
  const float* W_spkr    = (const float*)d_in[8];
  const float* conv_w    = (const float*)d_in[9];
  const float* W_dec     = (const float*)d_in[10];
  const float* W_speed   = (const float*)d_in[11];
  const float* Wp1       = (const float*)d_in[12];
  const float* bp1       = (const float*)d_in[13];
  const float* Wp2       = (const float*)d_in[14];
  const float* bp2       = (const float*)d_in[15];
  // d_in[16] = W_proj, d_in[17] = b_proj (b_proj cancels in softmax)
  const float* W_proj    = (const float*)d_in[16];

  float* out = (float*)d_out;

  int*   ws_idx    = (int*)d_ws;
  float* ws_bias   = (float*)((char*)d_ws + 256);
  float* ws_logits = (float*)((char*)d_ws + 256 + NB * 256 * sizeof(float));

  hipLaunchKernelGGL(prep_kernel, dim3(NB), dim3(1024), 0, stream,
                     pa, input_dec, spkr_vec, speed, Wp1, bp1, Wp2, bp2,
                     W_dec, W_spkr, W_speed, out, ws_idx, ws_bias);

  hipLaunchKernelGGL(band_kernel, dim3(NB, 5), dim3(256), 0, stream,
                     input_enc, pa, lengths, W_enc, b_enc, conv_w, W_proj,
                     ws_idx, ws_bias, ws_logits);

  hipLaunchKernelGGL(softmax_kernel, dim3(NB), dim3(64), 0, stream,
                     ws_logits, ws_idx, lengths, out);
}